// Round 13
// baseline (235.199 us; speedup 1.0000x reference)
//
#include <hip/hip_runtime.h>
#include <cstdint>
#include <cstddef>

// Problem constants (shapes fixed by the reference)
#define F_IN   128
#define HC1    64    // heads1*ch1 = 8*8
#define CH2_   16
#define NB     64    // batch graphs
#define BUKPAD 8192  // per-bucket padding (avg fill ~4350 for E=1.6M, N=100K)

typedef __attribute__((ext_vector_type(8))) short bf16x8;
typedef __attribute__((ext_vector_type(4))) float f32x4;

__global__ void fill_f32(float* __restrict__ p, float v, int n) {
  int i = blockIdx.x * blockDim.x + threadIdx.x;
  int stride = gridDim.x * blockDim.x;
  for (; i < n; i += stride) p[i] = v;
}

__device__ __forceinline__ unsigned short f2bf_rne(float v) {
  unsigned int u = __float_as_uint(v);
  unsigned int r = (u + 0x7FFFu + ((u >> 16) & 1u)) >> 16;   // round-nearest-even
  return (unsigned short)r;
}
__device__ __forceinline__ float bf2f(unsigned short b) {
  return __uint_as_float((unsigned int)b << 16);              // exact
}

// ---------------- DPP cross-lane reductions (full-rate VALU, no LDS pipe) -----
template<int CTRL>
__device__ __forceinline__ float dpp_add(float v) {
  int j = __builtin_amdgcn_update_dpp(0, __float_as_int(v), CTRL, 0xF, 0xF, true);
  return v + __int_as_float(j);
}
__device__ __forceinline__ float sum16_dpp(float v) {  // sum over each 16-lane row
  v = dpp_add<0xB1>(v);
  v = dpp_add<0x4E>(v);
  v = dpp_add<0x141>(v);
  v = dpp_add<0x140>(v);  // row_mirror
  return v;
}

// ---------------- Layer-1 GEMM on matrix cores (round-11, unchanged) ----------
__global__ void build_wfrag(const float* __restrict__ Wl, const float* __restrict__ Wr,
                            unsigned short* __restrict__ wfrag) {
  int idx = blockIdx.x * 256 + threadIdx.x;
  if (idx >= 16384) return;
  int e    = idx & 7;
  int lane = (idx >> 3) & 63;
  int tile = (idx >> 9) & 7;
  int ks   = idx >> 12;
  int k    = ks * 32 + (lane >> 4) * 8 + e;
  int col  = tile * 16 + (lane & 15);
  float v = (col < 64) ? Wl[k * 64 + col] : Wr[k * 64 + (col - 64)];
  wfrag[idx] = f2bf_rne(v);
}

__global__ __launch_bounds__(256) void gemm_mfma_l1(
    const float* __restrict__ x, const unsigned short* __restrict__ wfrag,
    const float* __restrict__ bl, const float* __restrict__ br,
    unsigned short* __restrict__ ya, float* __restrict__ yb, int n) {
  constexpr int RP = 136;                       // row stride in bf16 (128+8 pad)
  __shared__ __align__(16) char smem[34816 + 32768];
  unsigned short* axhi = (unsigned short*)smem;             // 17408 B
  unsigned short* axlo = (unsigned short*)(smem + 17408);   // 17408 B
  unsigned short* wf   = (unsigned short*)(smem + 34816);   // 32768 B
  float* outs = (float*)smem;                  // epilogue overlay

  const int t = threadIdx.x;
  const int node0 = blockIdx.x * 64;

  for (int i = t; i < 2048; i += 256)
    reinterpret_cast<int4*>(wf)[i] = reinterpret_cast<const int4*>(wfrag)[i];
  for (int i = t; i < 64 * 32; i += 256) {
    int row = i >> 5, kk = (i & 31) * 4;
    int node = node0 + row;
    float4 v = make_float4(0.f, 0.f, 0.f, 0.f);
    if (node < n) v = *reinterpret_cast<const float4*>(x + (size_t)node * 128 + kk);
    ushort4 hi, lo;
    hi.x = f2bf_rne(v.x); lo.x = f2bf_rne(v.x - bf2f(hi.x));
    hi.y = f2bf_rne(v.y); lo.y = f2bf_rne(v.y - bf2f(hi.y));
    hi.z = f2bf_rne(v.z); lo.z = f2bf_rne(v.z - bf2f(hi.z));
    hi.w = f2bf_rne(v.w); lo.w = f2bf_rne(v.w - bf2f(hi.w));
    *reinterpret_cast<ushort4*>(axhi + row * RP + kk) = hi;
    *reinterpret_cast<ushort4*>(axlo + row * RP + kk) = lo;
  }
  __syncthreads();

  const int wv   = t >> 6;
  const int lane = t & 63;
  const int mrow = lane & 15;
  const int kg   = lane >> 4;
  f32x4 acc[8];
#pragma unroll
  for (int i = 0; i < 8; ++i) acc[i] = (f32x4){0.f, 0.f, 0.f, 0.f};
  const int abase = (wv * 16 + mrow) * RP;
#pragma unroll
  for (int ks = 0; ks < 4; ++ks) {
    int aoff = abase + ks * 32 + kg * 8;
    bf16x8 ahi = *reinterpret_cast<const bf16x8*>(axhi + aoff);
    bf16x8 alo = *reinterpret_cast<const bf16x8*>(axlo + aoff);
#pragma unroll
    for (int tl = 0; tl < 8; ++tl) {
      bf16x8 b = *reinterpret_cast<const bf16x8*>(wf + ((ks * 8 + tl) * 64 + lane) * 8);
      acc[tl] = __builtin_amdgcn_mfma_f32_16x16x32_bf16(alo, b, acc[tl], 0, 0, 0);
      acc[tl] = __builtin_amdgcn_mfma_f32_16x16x32_bf16(ahi, b, acc[tl], 0, 0, 0);
    }
  }
  __syncthreads();
#pragma unroll
  for (int tl = 0; tl < 8; ++tl)
#pragma unroll
    for (int r = 0; r < 4; ++r) {
      int row = wv * 16 + kg * 4 + r;
      outs[row * 128 + tl * 16 + mrow] = acc[tl][r];
    }
  __syncthreads();
  for (int i = t; i < 64 * 64; i += 256) {
    int row = i >> 6, col = i & 63;
    int node = node0 + row;
    if (node < n) ya[(size_t)node * 64 + col] = f2bf_rne(outs[row * 128 + col] + bl[col]);
  }
  for (int i = t; i < 64 * 64; i += 256) {
    int row = i >> 6, col = i & 63;
    int node = node0 + row;
    if (node < n) yb[(size_t)node * 64 + col] = outs[row * 128 + 64 + col] + br[col];
  }
}

// ---------------- CSR build via 2-pass bucketed counting sort -----------------

__global__ void bucket_scatter(const int* __restrict__ ei, int E, int E2,
                               int* __restrict__ gcnt, int* __restrict__ gbuk) {
  __shared__ int hbase[512];
  __shared__ int hcnt[512];
  const int t = threadIdx.x;
  for (int i = t; i < 512; i += 256) { hbase[i] = 0; hcnt[i] = 0; }
  __syncthreads();
  int srcs[32], dsts[32];
  const int tile0 = blockIdx.x * 8192;
#pragma unroll
  for (int k = 0; k < 32; ++k) {
    int e = tile0 + k * 256 + t;          // coalesced
    int s = -1, d = 0;
    if (e < E2) {
      if (e < E) { s = ei[e]; d = ei[E + e]; } else { s = d = e - E; }
      atomicAdd(&hbase[d >> 8], 1);       // LDS atomic
    }
    srcs[k] = s; dsts[k] = d;
  }
  __syncthreads();
  for (int i = t; i < 512; i += 256) {
    int c = hbase[i];
    hbase[i] = (c > 0) ? atomicAdd(&gcnt[i], c) : 0;
  }
  __syncthreads();
#pragma unroll
  for (int k = 0; k < 32; ++k) {
    if (srcs[k] >= 0) {
      int d = dsts[k], b = d >> 8;
      int r = atomicAdd(&hcnt[b], 1);
      int pl = hbase[b] + r;
      if (pl < BUKPAD) gbuk[(size_t)b * BUKPAD + pl] = (srcs[k] << 8) | (d & 255);
    }
  }
}

__global__ void bucket_prefix(const int* __restrict__ gcnt, int nbuk,
                              int* __restrict__ gbase, int* __restrict__ row_start, int n) {
  int lane = threadIdx.x;  // 64 threads
  int carry = 0;
  for (int basei = 0; basei < nbuk; basei += 64) {
    int i = basei + lane;
    int orig = (i < nbuk) ? gcnt[i] : 0;
    int v = orig;
    for (int off = 1; off < 64; off <<= 1) {
      int u = __shfl_up(v, off);
      if (lane >= off) v += u;
    }
    if (i < nbuk) gbase[i] = carry + v - orig;
    carry += __shfl(v, 63);
  }
  if (lane == 0) row_start[n] = carry;    // == E2
}

__global__ void bucket_csr(const int* __restrict__ gcnt, const int* __restrict__ gbase,
                           const int* __restrict__ gbuk,
                           int* __restrict__ row_start, int* __restrict__ csr_src, int n) {
  const int b = blockIdx.x;
  const int t = threadIdx.x;
  const int node0 = b << 8;
  const int cntb = min(gcnt[b], BUKPAD);
  const int base = gbase[b];
  const int* buk = gbuk + (size_t)b * BUKPAD;
  __shared__ int h[256];
  __shared__ int off[256];
  h[t] = 0;
  __syncthreads();
  for (int i = t; i < cntb; i += 256) atomicAdd(&h[buk[i] & 255], 1);
  __syncthreads();
  off[t] = h[t];
  __syncthreads();
  for (int o = 1; o < 256; o <<= 1) {
    int u = (t >= o) ? off[t - o] : 0;
    __syncthreads();
    off[t] += u;
    __syncthreads();
  }
  int excl = off[t] - h[t];
  if (node0 + t < n) row_start[node0 + t] = base + excl;
  h[t] = excl;
  __syncthreads();
  for (int i = t; i < cntb; i += 256) {
    int p = buk[i];
    int r = atomicAdd(&h[p & 255], 1);
    csr_src[base + r] = p >> 8;
  }
}

// ---------------- Fused layer 1 + layer-2 linear transforms -------------------
// Round-13: wave-uniform j-step skip (deg~17 vs 16-edge quantization wasted
// ~47% of edge-slot VALU as masked compute; guard c0+j*4<lim is uniform ->
// s_cbranch, skipped steps never issue gathers) + 32-bit byte-offset gathers
// (xl table is 12.8MB; pre-shift src ids <<7 before the shfl).
__global__ void fused_layer1(const int* __restrict__ row_start, const int* __restrict__ csr_src,
                             const unsigned short* __restrict__ xl, const float* __restrict__ xr,
                             const float* __restrict__ att, const float* __restrict__ bias,
                             const float* __restrict__ Wl2, const float* __restrict__ bl2,
                             const float* __restrict__ Wr2, const float* __restrict__ br2,
                             float* __restrict__ xl2, float* __restrict__ xr2, int n) {
  __shared__ float Ws2[64 * 32];   // [l][j]: j<16 -> Wl2 col j, j>=16 -> Wr2 col j-16
  __shared__ float b2s[32];
  const int t = threadIdx.x;
  for (int i = t; i < 64 * 16; i += 256) {
    int l = i >> 4, j = i & 15;
    Ws2[l * 32 + j]      = Wl2[i];
    Ws2[l * 32 + 16 + j] = Wr2[i];
  }
  if (t < 16) { b2s[t] = bl2[t]; b2s[16 + t] = br2[t]; }
  __syncthreads();

  const int node = blockIdx.x * 4 + (t >> 6);
  if (node >= n) return;
  const int lane = t & 63;
  const int g = lane >> 4;            // edge slot 0..3 within a chunk
  const int q = lane & 15;            // channels 4q..4q+3, head q>>1
  const float4 attv = *reinterpret_cast<const float4*>(att + q * 4);
  const float4 xrv  = *reinterpret_cast<const float4*>(xr + (size_t)node * 64 + q * 4);
  const char* xlb = (const char*)xl + q * 8;     // lane's channel base (q*4 ushorts)
  const int beg = row_start[node];
  const int total = row_start[node + 1] - beg;   // >= 1 (self loop)
  const float NEGB = -3.0e38f;                   // masked slots: exp -> 0
  float den = 0.0f;
  float4 acc = make_float4(0.f, 0.f, 0.f, 0.f);

  for (int base = 0; base < total; base += 64) {
    int idx = base + lane;
    int sb = csr_src[beg + (idx < total ? idx : total - 1)] << 7;  // row byte offset
    const int lim = min(64, total - base);
    for (int c0 = 0; c0 < lim; c0 += 16) {
      int sv[4]; ushort4 u[4];
#pragma unroll
      for (int j = 0; j < 4; ++j)
        if (c0 + j * 4 < lim) {                  // wave-uniform guard
          sv[j] = __shfl(sb, c0 + j * 4 + g);    // bpermute, no mem dep
          u[j] = *reinterpret_cast<const ushort4*>(xlb + (unsigned)sv[j]);
        }
#pragma unroll
      for (int j = 0; j < 4; ++j)
        if (c0 + j * 4 < lim) {
          int ii = c0 + j * 4 + g;
          float x0 = bf2f(u[j].x), x1 = bf2f(u[j].y), x2 = bf2f(u[j].z), x3 = bf2f(u[j].w);
          float a0 = x0 + xrv.x; a0 = fmaxf(a0, 0.2f * a0);
          float a1 = x1 + xrv.y; a1 = fmaxf(a1, 0.2f * a1);
          float a2 = x2 + xrv.z; a2 = fmaxf(a2, 0.2f * a2);
          float a3 = x3 + xrv.w; a3 = fmaxf(a3, 0.2f * a3);
          float p = a0 * attv.x + a1 * attv.y + a2 * attv.z + a3 * attv.w;
          float v = dpp_add<0xB1>(p);            // head logit on pair lanes
          float ex = __expf(ii < lim ? v : NEGB);
          den  += ex;
          acc.x += ex * x0; acc.y += ex * x1;
          acc.z += ex * x2; acc.w += ex * x3;
        }
    }
  }
  // combine the 4 edge slots (pair lanes already share den)
  acc.x += __shfl_xor(acc.x, 16); acc.y += __shfl_xor(acc.y, 16);
  acc.z += __shfl_xor(acc.z, 16); acc.w += __shfl_xor(acc.w, 16);
  acc.x += __shfl_xor(acc.x, 32); acc.y += __shfl_xor(acc.y, 32);
  acc.z += __shfl_xor(acc.z, 32); acc.w += __shfl_xor(acc.w, 32);
  den += __shfl_xor(den, 16);
  den += __shfl_xor(den, 32);
  const float inv = 1.0f / (den + 1e-16f);
  const float4 bi = *reinterpret_cast<const float4*>(bias + q * 4);
  float o0 = acc.x * inv + bi.x; o0 = o0 > 0.f ? o0 : __expf(o0) - 1.0f;  // elu
  float o1 = acc.y * inv + bi.y; o1 = o1 > 0.f ? o1 : __expf(o1) - 1.0f;
  float o2 = acc.z * inv + bi.z; o2 = o2 > 0.f ? o2 : __expf(o2) - 1.0f;
  float o3 = acc.w * inv + bi.w; o3 = o3 > 0.f ? o3 : __expf(o3) - 1.0f;

  // redistribute h1 to one channel per lane (channel = lane)
  int srcl = lane >> 2;
  float c0v = __shfl(o0, srcl);
  float c1v = __shfl(o1, srcl);
  float c2v = __shfl(o2, srcl);
  float c3v = __shfl(o3, srcl);
  int r = lane & 3;
  float o = (r == 0) ? c0v : (r == 1) ? c1v : (r == 2) ? c2v : c3v;

  // in-wave layer-2 transforms: out[j] = sum_l o_l * Ws2[l][j]
  const int j    = lane & 31;
  const int half = lane >> 5;              // 0: l=0..31, 1: l=32..63
  float part2 = 0.0f;
#pragma unroll 8
  for (int l = 0; l < 32; ++l) {
    int src = half * 32 + l;
    float ov = __shfl(o, src);
    part2 += ov * Ws2[src * 32 + j];
  }
  part2 += __shfl_xor(part2, 32);          // combine the two halves
  if (lane < 16)      xl2[(size_t)node * 16 + j]        = part2 + b2s[j];
  else if (lane < 32) xr2[(size_t)node * 16 + (j - 16)] = part2 + b2s[j];
}

// ---------------- Fused layer 2 (round-12 window version, unchanged) ----------
__global__ void fused_layer2(const int* __restrict__ row_start, const int* __restrict__ csr_src,
                             const float* __restrict__ xl, const float* __restrict__ xr,
                             const float* __restrict__ att, const float* __restrict__ bias,
                             float* __restrict__ out, int n) {
  int node = blockIdx.x * 16 + (threadIdx.x >> 4);
  if (node >= n) return;
  const int lane = threadIdx.x & 63;
  const int c = lane & 15;
  const int gbase = lane & 48;             // base lane of this node's 16-lane group
  const float attv = att[c];
  const float xrv  = xr[(size_t)node * 16 + c];
  const int beg = row_start[node];
  const int total = row_start[node + 1] - beg;   // >= 1
  const float NEGB = -3.0e38f;
  float den = 0.0f, acc = 0.0f;

  for (int base = 0; base < total; base += 16) {
    int wi = base + c;
    int sidx = csr_src[beg + (wi < total ? wi : total - 1)];   // coalesced window
    const int lim = min(16, total - base);
    for (int c0 = 0; c0 < lim; c0 += 4) {
      int sv[4]; float xv[4];
#pragma unroll
      for (int j = 0; j < 4; ++j) sv[j] = __shfl(sidx, gbase + c0 + j);
#pragma unroll
      for (int j = 0; j < 4; ++j)                 // 4 gathers in flight
        xv[j] = xl[(size_t)sv[j] * 16 + c];
#pragma unroll
      for (int j = 0; j < 4; ++j) {
        float a = xv[j] + xrv; a = fmaxf(a, 0.2f * a);
        float v = sum16_dpp(a * attv);
        float ex = __expf((c0 + j) < lim ? v : NEGB);
        den += ex;
        acc += ex * xv[j];
      }
    }
  }
  out[(size_t)node * 16 + c] = acc / (den + 1e-16f) + bias[c];   // no elu after conv2
}

// ---------------- Pooling + classifier ---------------------------------------

__global__ void pool_kernel(const float* __restrict__ h2, const int* __restrict__ batch,
                            float* __restrict__ sums, float* __restrict__ cnts, int n) {
  __shared__ float ls[NB * CH2_];
  __shared__ float lc[NB];
  for (int i = threadIdx.x; i < NB * CH2_; i += blockDim.x) ls[i] = 0.0f;
  for (int i = threadIdx.x; i < NB; i += blockDim.x) lc[i] = 0.0f;
  __syncthreads();
  int total = n * 16;
  int stride = gridDim.x * blockDim.x;
  for (int i = blockIdx.x * blockDim.x + threadIdx.x; i < total; i += stride) {
    int node = i >> 4, c = i & 15;
    int b = batch[node];
    atomicAdd(&ls[b * 16 + c], h2[i]);
    if (c == 0) atomicAdd(&lc[b], 1.0f);
  }
  __syncthreads();
  for (int i = threadIdx.x; i < NB * CH2_; i += blockDim.x)
    if (ls[i] != 0.0f) atomicAdd(&sums[i], ls[i]);
  for (int i = threadIdx.x; i < NB; i += blockDim.x)
    if (lc[i] != 0.0f) atomicAdd(&cnts[i], lc[i]);
}

__global__ void classifier(const float* __restrict__ sums, const float* __restrict__ cnts,
                           const float* __restrict__ Wc, const float* __restrict__ bc,
                           float* __restrict__ out) {
  int b = threadIdx.x;
  if (b >= NB) return;
  float cnt = cnts[b];
  cnt = cnt > 1.0f ? cnt : 1.0f;
  float acc = 0.0f;
  for (int c = 0; c < 16; ++c) {
    float p = sums[b * 16 + c] / cnt;
    out[NB + b * 16 + c] = p;   // pooled, output 1
    acc += p * Wc[c];
  }
  out[b] = acc + bc[0];         // out, output 0
}

extern "C" void kernel_launch(void* const* d_in, const int* in_sizes, int n_in,
                              void* d_out, int out_size, void* d_ws, size_t ws_size,
                              hipStream_t stream) {
  const float* x     = (const float*)d_in[0];
  const int*   ei    = (const int*)d_in[1];
  const int*   batch = (const int*)d_in[2];
  const float* Wl1   = (const float*)d_in[3];
  const float* bl1   = (const float*)d_in[4];
  const float* Wr1   = (const float*)d_in[5];
  const float* br1   = (const float*)d_in[6];
  const float* att1  = (const float*)d_in[7];
  const float* bias1 = (const float*)d_in[8];
  const float* Wl2   = (const float*)d_in[9];
  const float* bl2   = (const float*)d_in[10];
  const float* Wr2   = (const float*)d_in[11];
  const float* br2   = (const float*)d_in[12];
  const float* att2  = (const float*)d_in[13];
  const float* bias2 = (const float*)d_in[14];
  const float* Wc    = (const float*)d_in[15];
  const float* bc    = (const float*)d_in[16];
  float* out = (float*)d_out;

  const int N  = in_sizes[0] / F_IN;
  const int E  = in_sizes[1] / 2;
  const int E2 = E + N;
  const int nbuk = (N + 255) >> 8;   // 391 for N=100K (<=512 assumed)

  // Workspace layout
  float* ws   = (float*)d_ws;
  unsigned short* xl1 = (unsigned short*)ws;   // N*64 bf16
  float* xr1  = (float*)(xl1 + (size_t)N * 64);// N*64 fp32
  float* xl2  = xr1 + (size_t)N * 64;          // N*16
  float* xr2  = xl2 + (size_t)N * 16;          // N*16
  float* h2   = xr2 + (size_t)N * 16;          // N*16
  int* irow   = (int*)(h2 + (size_t)N * 16);   // N+1
  int* icsr   = irow + (N + 1);                // E2
  int* gcnt   = icsr + E2;                     // 512
  int* gbase  = gcnt + 512;                    // 512+1
  int* gbuk   = gbase + 513 + 2;               // nbuk*BUKPAD
  unsigned short* wfrag =
      (unsigned short*)(((uintptr_t)(gbuk + (size_t)nbuk * BUKPAD) + 15) & ~(uintptr_t)15);
  float* sums = (float*)(wfrag + 16384);       // NB*16
  float* cnts = sums + NB * CH2_;              // NB

  // ---- CSR build (2-pass bucketed counting sort) ----
  fill_f32<<<1, 256, 0, stream>>>((float*)gcnt, 0.0f, 512);
  bucket_scatter<<<(E2 + 8191) / 8192, 256, 0, stream>>>(ei, E, E2, gcnt, gbuk);
  bucket_prefix<<<1, 64, 0, stream>>>(gcnt, nbuk, gbase, irow, N);
  bucket_csr<<<nbuk, 256, 0, stream>>>(gcnt, gbase, gbuk, irow, icsr, N);

  // ---- layer 1 GEMM on matrix cores (xl bf16, xr fp32) ----
  build_wfrag<<<64, 256, 0, stream>>>(Wl1, Wr1, wfrag);
  gemm_mfma_l1<<<(N + 63) / 64, 256, 0, stream>>>(x, wfrag, bl1, br1, xl1, xr1, N);

  // ---- fused layer 1 + layer-2 linear transforms ----
  fused_layer1<<<(N + 3) / 4, 256, 0, stream>>>(
      irow, icsr, xl1, xr1, att1, bias1, Wl2, bl2, Wr2, br2, xl2, xr2, N);

  // ---- fused layer 2 ----
  fused_layer2<<<(N + 15) / 16, 256, 0, stream>>>(irow, icsr, xl2, xr2, att2, bias2, h2, N);

  // ---- pooling + classifier ----
  fill_f32<<<1, 256, 0, stream>>>(sums, 0.0f, NB * CH2_ + NB);
  pool_kernel<<<256, 256, 0, stream>>>(h2, batch, sums, cnts, N);
  classifier<<<1, 64, 0, stream>>>(sums, cnts, Wc, bc, out);
}

// Round 14
// 213.102 us; speedup vs baseline: 1.1037x; 1.1037x over previous
//
#include <hip/hip_runtime.h>
#include <cstdint>
#include <cstddef>

// Problem constants (shapes fixed by the reference)
#define F_IN   128
#define HC1    64    // heads1*ch1 = 8*8
#define CH2_   16
#define NB     64    // batch graphs
#define BUKPAD 8192  // per-bucket padding (avg fill ~4350 for E=1.6M, N=100K)

typedef __attribute__((ext_vector_type(8))) short bf16x8;
typedef __attribute__((ext_vector_type(4))) float f32x4;

__global__ void fill_f32(float* __restrict__ p, float v, int n) {
  int i = blockIdx.x * blockDim.x + threadIdx.x;
  int stride = gridDim.x * blockDim.x;
  for (; i < n; i += stride) p[i] = v;
}

__device__ __forceinline__ unsigned short f2bf_rne(float v) {
  unsigned int u = __float_as_uint(v);
  unsigned int r = (u + 0x7FFFu + ((u >> 16) & 1u)) >> 16;   // round-nearest-even
  return (unsigned short)r;
}
__device__ __forceinline__ float bf2f(unsigned short b) {
  return __uint_as_float((unsigned int)b << 16);              // exact
}

// ---------------- DPP cross-lane reductions (full-rate VALU, no LDS pipe) -----
template<int CTRL>
__device__ __forceinline__ float dpp_add(float v) {
  int j = __builtin_amdgcn_update_dpp(0, __float_as_int(v), CTRL, 0xF, 0xF, true);
  return v + __int_as_float(j);
}
__device__ __forceinline__ float sum16_dpp(float v) {  // sum over each 16-lane row
  v = dpp_add<0xB1>(v);
  v = dpp_add<0x4E>(v);
  v = dpp_add<0x141>(v);
  v = dpp_add<0x140>(v);  // row_mirror
  return v;
}

// ---------------- W-fragment swizzle for the MFMA GEMM ------------------------
__global__ void build_wfrag(const float* __restrict__ Wl, const float* __restrict__ Wr,
                            unsigned short* __restrict__ wfrag) {
  int idx = blockIdx.x * 256 + threadIdx.x;
  if (idx >= 16384) return;
  int e    = idx & 7;
  int lane = (idx >> 3) & 63;
  int tile = (idx >> 9) & 7;
  int ks   = idx >> 12;
  int k    = ks * 32 + (lane >> 4) * 8 + e;
  int col  = tile * 16 + (lane & 15);
  float v = (col < 64) ? Wl[k * 64 + col] : Wr[k * 64 + (col - 64)];
  wfrag[idx] = f2bf_rne(v);
}

// ---------------- MEGA kernel: bucket_scatter || gemm_mfma_l1 -----------------
// The two chains are independent (scatter: ei -> gbuk/gcnt; gemm: x,W -> xl/xr),
// so co-scheduling them in one dispatch overlaps the latency/atomic-bound
// scatter with the MFMA-bound GEMM instead of serializing ~30+~25 us.

__device__ void scatter_body(char* smem, const int* __restrict__ ei, int E, int E2,
                             int* __restrict__ gcnt, int* __restrict__ gbuk, int blk) {
  int* hbase = (int*)smem;          // 512 ints
  int* hcnt  = hbase + 512;         // 512 ints
  const int t = threadIdx.x;
  for (int i = t; i < 512; i += 256) { hbase[i] = 0; hcnt[i] = 0; }
  __syncthreads();
  int srcs[32], dsts[32];
  const int tile0 = blk * 8192;
#pragma unroll
  for (int k = 0; k < 32; ++k) {
    int e = tile0 + k * 256 + t;          // coalesced
    int s = -1, d = 0;
    if (e < E2) {
      if (e < E) { s = ei[e]; d = ei[E + e]; } else { s = d = e - E; }
      atomicAdd(&hbase[d >> 8], 1);       // LDS atomic
    }
    srcs[k] = s; dsts[k] = d;
  }
  __syncthreads();
  for (int i = t; i < 512; i += 256) {    // reserve this block's run per bucket
    int c = hbase[i];
    hbase[i] = (c > 0) ? atomicAdd(&gcnt[i], c) : 0;
  }
  __syncthreads();
#pragma unroll
  for (int k = 0; k < 32; ++k) {
    if (srcs[k] >= 0) {
      int d = dsts[k], b = d >> 8;
      int r = atomicAdd(&hcnt[b], 1);
      int pl = hbase[b] + r;
      if (pl < BUKPAD) gbuk[(size_t)b * BUKPAD + pl] = (srcs[k] << 8) | (d & 255);
    }
  }
}

__device__ void gemm_body(char* smem, const float* __restrict__ x,
                          const unsigned short* __restrict__ wfrag,
                          const float* __restrict__ bl, const float* __restrict__ br,
                          unsigned short* __restrict__ ya, float* __restrict__ yb,
                          int n, int blk) {
  constexpr int RP = 136;                       // row stride in bf16 (128+8 pad)
  unsigned short* axhi = (unsigned short*)smem;             // 17408 B
  unsigned short* axlo = (unsigned short*)(smem + 17408);   // 17408 B
  unsigned short* wf   = (unsigned short*)(smem + 34816);   // 32768 B
  float* outs = (float*)smem;                  // epilogue overlay

  const int t = threadIdx.x;
  const int node0 = blk * 64;

  for (int i = t; i < 2048; i += 256)
    reinterpret_cast<int4*>(wf)[i] = reinterpret_cast<const int4*>(wfrag)[i];
  for (int i = t; i < 64 * 32; i += 256) {
    int row = i >> 5, kk = (i & 31) * 4;
    int node = node0 + row;
    float4 v = make_float4(0.f, 0.f, 0.f, 0.f);
    if (node < n) v = *reinterpret_cast<const float4*>(x + (size_t)node * 128 + kk);
    ushort4 hi, lo;
    hi.x = f2bf_rne(v.x); lo.x = f2bf_rne(v.x - bf2f(hi.x));
    hi.y = f2bf_rne(v.y); lo.y = f2bf_rne(v.y - bf2f(hi.y));
    hi.z = f2bf_rne(v.z); lo.z = f2bf_rne(v.z - bf2f(hi.z));
    hi.w = f2bf_rne(v.w); lo.w = f2bf_rne(v.w - bf2f(hi.w));
    *reinterpret_cast<ushort4*>(axhi + row * RP + kk) = hi;
    *reinterpret_cast<ushort4*>(axlo + row * RP + kk) = lo;
  }
  __syncthreads();

  const int wv   = t >> 6;
  const int lane = t & 63;
  const int mrow = lane & 15;
  const int kg   = lane >> 4;
  f32x4 acc[8];
#pragma unroll
  for (int i = 0; i < 8; ++i) acc[i] = (f32x4){0.f, 0.f, 0.f, 0.f};
  const int abase = (wv * 16 + mrow) * RP;
#pragma unroll
  for (int ks = 0; ks < 4; ++ks) {
    int aoff = abase + ks * 32 + kg * 8;
    bf16x8 ahi = *reinterpret_cast<const bf16x8*>(axhi + aoff);
    bf16x8 alo = *reinterpret_cast<const bf16x8*>(axlo + aoff);
#pragma unroll
    for (int tl = 0; tl < 8; ++tl) {
      bf16x8 b = *reinterpret_cast<const bf16x8*>(wf + ((ks * 8 + tl) * 64 + lane) * 8);
      acc[tl] = __builtin_amdgcn_mfma_f32_16x16x32_bf16(alo, b, acc[tl], 0, 0, 0);
      acc[tl] = __builtin_amdgcn_mfma_f32_16x16x32_bf16(ahi, b, acc[tl], 0, 0, 0);
    }
  }
  __syncthreads();
#pragma unroll
  for (int tl = 0; tl < 8; ++tl)
#pragma unroll
    for (int r = 0; r < 4; ++r) {
      int row = wv * 16 + kg * 4 + r;          // C/D: row=(lane>>4)*4+reg
      outs[row * 128 + tl * 16 + mrow] = acc[tl][r];
    }
  __syncthreads();
  for (int i = t; i < 64 * 64; i += 256) {
    int row = i >> 6, col = i & 63;
    int node = node0 + row;
    if (node < n) ya[(size_t)node * 64 + col] = f2bf_rne(outs[row * 128 + col] + bl[col]);
  }
  for (int i = t; i < 64 * 64; i += 256) {
    int row = i >> 6, col = i & 63;
    int node = node0 + row;
    if (node < n) yb[(size_t)node * 64 + col] = outs[row * 128 + 64 + col] + br[col];
  }
}

__global__ __launch_bounds__(256) void mega_scatter_gemm(
    const int* __restrict__ ei, int E, int E2,
    int* __restrict__ gcnt, int* __restrict__ gbuk, int nscat,
    const float* __restrict__ x, const unsigned short* __restrict__ wfrag,
    const float* __restrict__ bl, const float* __restrict__ br,
    unsigned short* __restrict__ ya, float* __restrict__ yb, int n) {
  __shared__ __align__(16) char smem[34816 + 32768];
  if ((int)blockIdx.x < nscat)
    scatter_body(smem, ei, E, E2, gcnt, gbuk, blockIdx.x);
  else
    gemm_body(smem, x, wfrag, bl, br, ya, yb, n, blockIdx.x - nscat);
}

// ---------------- CSR finish: prefix + per-bucket counting sort ---------------

__global__ void bucket_prefix(const int* __restrict__ gcnt, int nbuk,
                              int* __restrict__ gbase, int* __restrict__ row_start, int n) {
  int lane = threadIdx.x;  // 64 threads
  int carry = 0;
  for (int basei = 0; basei < nbuk; basei += 64) {
    int i = basei + lane;
    int orig = (i < nbuk) ? gcnt[i] : 0;
    int v = orig;
    for (int off = 1; off < 64; off <<= 1) {
      int u = __shfl_up(v, off);
      if (lane >= off) v += u;
    }
    if (i < nbuk) gbase[i] = carry + v - orig;
    carry += __shfl(v, 63);
  }
  if (lane == 0) row_start[n] = carry;    // == E2
}

__global__ void bucket_csr(const int* __restrict__ gcnt, const int* __restrict__ gbase,
                           const int* __restrict__ gbuk,
                           int* __restrict__ row_start, int* __restrict__ csr_src, int n) {
  const int b = blockIdx.x;
  const int t = threadIdx.x;
  const int node0 = b << 8;
  const int cntb = min(gcnt[b], BUKPAD);
  const int base = gbase[b];
  const int* buk = gbuk + (size_t)b * BUKPAD;
  __shared__ int h[256];
  __shared__ int off[256];
  h[t] = 0;
  __syncthreads();
  for (int i = t; i < cntb; i += 256) atomicAdd(&h[buk[i] & 255], 1);
  __syncthreads();
  off[t] = h[t];
  __syncthreads();
  for (int o = 1; o < 256; o <<= 1) {
    int u = (t >= o) ? off[t - o] : 0;
    __syncthreads();
    off[t] += u;
    __syncthreads();
  }
  int excl = off[t] - h[t];
  if (node0 + t < n) row_start[node0 + t] = base + excl;
  h[t] = excl;
  __syncthreads();
  for (int i = t; i < cntb; i += 256) {
    int p = buk[i];
    int r = atomicAdd(&h[p & 255], 1);
    csr_src[base + r] = p >> 8;
  }
}

// ---------------- Fused layer 1 + layer-2 linear transforms -------------------
// Round-14: REVERTED to the round-12 inner loop (4 unguarded independent
// gathers; round-13's uniform guards broke load clustering: 94->101us,
// VALU 75->60%). fused_layer1 is at the L3 random-gather service floor
// (~1.1 TB/s on a 12.8MB table from 8 XCDs) -- three structures all ~93-101us.
// xl2 output now bf16 (layer-2's gather table 6.4->3.2MB: fits per-XCD L2).
__global__ void fused_layer1(const int* __restrict__ row_start, const int* __restrict__ csr_src,
                             const unsigned short* __restrict__ xl, const float* __restrict__ xr,
                             const float* __restrict__ att, const float* __restrict__ bias,
                             const float* __restrict__ Wl2, const float* __restrict__ bl2,
                             const float* __restrict__ Wr2, const float* __restrict__ br2,
                             unsigned short* __restrict__ xl2, float* __restrict__ xr2, int n) {
  __shared__ float Ws2[64 * 32];   // [l][j]: j<16 -> Wl2 col j, j>=16 -> Wr2 col j-16
  __shared__ float b2s[32];
  const int t = threadIdx.x;
  for (int i = t; i < 64 * 16; i += 256) {
    int l = i >> 4, j = i & 15;
    Ws2[l * 32 + j]      = Wl2[i];
    Ws2[l * 32 + 16 + j] = Wr2[i];
  }
  if (t < 16) { b2s[t] = bl2[t]; b2s[16 + t] = br2[t]; }
  __syncthreads();

  const int node = blockIdx.x * 4 + (t >> 6);
  if (node >= n) return;
  const int lane = t & 63;
  const int g = lane >> 4;            // edge slot 0..3 within a chunk
  const int q = lane & 15;            // channels 4q..4q+3, head q>>1
  const float4 attv = *reinterpret_cast<const float4*>(att + q * 4);
  const float4 xrv  = *reinterpret_cast<const float4*>(xr + (size_t)node * 64 + q * 4);
  const unsigned short* xlq = xl + q * 4;
  const int beg = row_start[node];
  const int total = row_start[node + 1] - beg;   // >= 1 (self loop)
  const float NEGB = -3.0e38f;                   // masked slots: exp -> 0
  float den = 0.0f;
  float4 acc = make_float4(0.f, 0.f, 0.f, 0.f);

  for (int base = 0; base < total; base += 64) {
    int idx = base + lane;
    int sidx = csr_src[beg + (idx < total ? idx : total - 1)];  // coalesced window
    const int lim = min(64, total - base);
    for (int c0 = 0; c0 < lim; c0 += 16) {
      int ii[4]; int sv[4]; ushort4 u[4];
#pragma unroll
      for (int j = 0; j < 4; ++j) ii[j] = c0 + j * 4 + g;
#pragma unroll
      for (int j = 0; j < 4; ++j) sv[j] = __shfl(sidx, ii[j]);  // bpermute, no mem dep
#pragma unroll
      for (int j = 0; j < 4; ++j)                              // 4 gathers in flight
        u[j] = *reinterpret_cast<const ushort4*>(xlq + (size_t)sv[j] * 64);
#pragma unroll
      for (int j = 0; j < 4; ++j) {
        float x0 = bf2f(u[j].x), x1 = bf2f(u[j].y), x2 = bf2f(u[j].z), x3 = bf2f(u[j].w);
        float a0 = x0 + xrv.x; a0 = fmaxf(a0, 0.2f * a0);
        float a1 = x1 + xrv.y; a1 = fmaxf(a1, 0.2f * a1);
        float a2 = x2 + xrv.z; a2 = fmaxf(a2, 0.2f * a2);
        float a3 = x3 + xrv.w; a3 = fmaxf(a3, 0.2f * a3);
        float p = a0 * attv.x + a1 * attv.y + a2 * attv.z + a3 * attv.w;
        float v = dpp_add<0xB1>(p);              // head logit on pair lanes
        float ex = __expf(ii[j] < lim ? v : NEGB);
        den  += ex;
        acc.x += ex * x0; acc.y += ex * x1;
        acc.z += ex * x2; acc.w += ex * x3;
      }
    }
  }
  // combine the 4 edge slots (pair lanes already share den)
  acc.x += __shfl_xor(acc.x, 16); acc.y += __shfl_xor(acc.y, 16);
  acc.z += __shfl_xor(acc.z, 16); acc.w += __shfl_xor(acc.w, 16);
  acc.x += __shfl_xor(acc.x, 32); acc.y += __shfl_xor(acc.y, 32);
  acc.z += __shfl_xor(acc.z, 32); acc.w += __shfl_xor(acc.w, 32);
  den += __shfl_xor(den, 16);
  den += __shfl_xor(den, 32);
  const float inv = 1.0f / (den + 1e-16f);
  const float4 bi = *reinterpret_cast<const float4*>(bias + q * 4);
  float o0 = acc.x * inv + bi.x; o0 = o0 > 0.f ? o0 : __expf(o0) - 1.0f;  // elu
  float o1 = acc.y * inv + bi.y; o1 = o1 > 0.f ? o1 : __expf(o1) - 1.0f;
  float o2 = acc.z * inv + bi.z; o2 = o2 > 0.f ? o2 : __expf(o2) - 1.0f;
  float o3 = acc.w * inv + bi.w; o3 = o3 > 0.f ? o3 : __expf(o3) - 1.0f;

  // redistribute h1 to one channel per lane (channel = lane)
  int srcl = lane >> 2;
  float c0v = __shfl(o0, srcl);
  float c1v = __shfl(o1, srcl);
  float c2v = __shfl(o2, srcl);
  float c3v = __shfl(o3, srcl);
  int r = lane & 3;
  float o = (r == 0) ? c0v : (r == 1) ? c1v : (r == 2) ? c2v : c3v;

  // in-wave layer-2 transforms: out[j] = sum_l o_l * Ws2[l][j]
  const int j    = lane & 31;
  const int half = lane >> 5;              // 0: l=0..31, 1: l=32..63
  float part2 = 0.0f;
#pragma unroll 8
  for (int l = 0; l < 32; ++l) {
    int src = half * 32 + l;
    float ov = __shfl(o, src);
    part2 += ov * Ws2[src * 32 + j];
  }
  part2 += __shfl_xor(part2, 32);          // combine the two halves
  if (lane < 16)      xl2[(size_t)node * 16 + j]        = f2bf_rne(part2 + b2s[j]);
  else if (lane < 32) xr2[(size_t)node * 16 + (j - 16)] = part2 + b2s[j];
}

// ---------------- Fused layer 2 (round-12 window version; bf16 xl table) ------
__global__ void fused_layer2(const int* __restrict__ row_start, const int* __restrict__ csr_src,
                             const unsigned short* __restrict__ xl, const float* __restrict__ xr,
                             const float* __restrict__ att, const float* __restrict__ bias,
                             float* __restrict__ out, int n) {
  int node = blockIdx.x * 16 + (threadIdx.x >> 4);
  if (node >= n) return;
  const int lane = threadIdx.x & 63;
  const int c = lane & 15;
  const int gbase = lane & 48;             // base lane of this node's 16-lane group
  const float attv = att[c];
  const float xrv  = xr[(size_t)node * 16 + c];
  const int beg = row_start[node];
  const int total = row_start[node + 1] - beg;   // >= 1
  const float NEGB = -3.0e38f;
  float den = 0.0f, acc = 0.0f;

  for (int base = 0; base < total; base += 16) {
    int wi = base + c;
    int sidx = csr_src[beg + (wi < total ? wi : total - 1)];   // coalesced window
    const int lim = min(16, total - base);
    for (int c0 = 0; c0 < lim; c0 += 4) {
      int sv[4]; float xv[4];
#pragma unroll
      for (int j = 0; j < 4; ++j) sv[j] = __shfl(sidx, gbase + c0 + j);
#pragma unroll
      for (int j = 0; j < 4; ++j)                 // 4 gathers in flight (L2-hot table)
        xv[j] = bf2f(xl[(size_t)sv[j] * 16 + c]);
#pragma unroll
      for (int j = 0; j < 4; ++j) {
        float a = xv[j] + xrv; a = fmaxf(a, 0.2f * a);
        float v = sum16_dpp(a * attv);
        float ex = __expf((c0 + j) < lim ? v : NEGB);
        den += ex;
        acc += ex * xv[j];
      }
    }
  }
  out[(size_t)node * 16 + c] = acc / (den + 1e-16f) + bias[c];   // no elu after conv2
}

// ---------------- Pooling + classifier ---------------------------------------

__global__ void pool_kernel(const float* __restrict__ h2, const int* __restrict__ batch,
                            float* __restrict__ sums, float* __restrict__ cnts, int n) {
  __shared__ float ls[NB * CH2_];
  __shared__ float lc[NB];
  for (int i = threadIdx.x; i < NB * CH2_; i += blockDim.x) ls[i] = 0.0f;
  for (int i = threadIdx.x; i < NB; i += blockDim.x) lc[i] = 0.0f;
  __syncthreads();
  int total = n * 16;
  int stride = gridDim.x * blockDim.x;
  for (int i = blockIdx.x * blockDim.x + threadIdx.x; i < total; i += stride) {
    int node = i >> 4, c = i & 15;
    int b = batch[node];
    atomicAdd(&ls[b * 16 + c], h2[i]);
    if (c == 0) atomicAdd(&lc[b], 1.0f);
  }
  __syncthreads();
  for (int i = threadIdx.x; i < NB * CH2_; i += blockDim.x)
    if (ls[i] != 0.0f) atomicAdd(&sums[i], ls[i]);
  for (int i = threadIdx.x; i < NB; i += blockDim.x)
    if (lc[i] != 0.0f) atomicAdd(&cnts[i], lc[i]);
}

__global__ void classifier(const float* __restrict__ sums, const float* __restrict__ cnts,
                           const float* __restrict__ Wc, const float* __restrict__ bc,
                           float* __restrict__ out) {
  int b = threadIdx.x;
  if (b >= NB) return;
  float cnt = cnts[b];
  cnt = cnt > 1.0f ? cnt : 1.0f;
  float acc = 0.0f;
  for (int c = 0; c < 16; ++c) {
    float p = sums[b * 16 + c] / cnt;
    out[NB + b * 16 + c] = p;   // pooled, output 1
    acc += p * Wc[c];
  }
  out[b] = acc + bc[0];         // out, output 0
}

extern "C" void kernel_launch(void* const* d_in, const int* in_sizes, int n_in,
                              void* d_out, int out_size, void* d_ws, size_t ws_size,
                              hipStream_t stream) {
  const float* x     = (const float*)d_in[0];
  const int*   ei    = (const int*)d_in[1];
  const int*   batch = (const int*)d_in[2];
  const float* Wl1   = (const float*)d_in[3];
  const float* bl1   = (const float*)d_in[4];
  const float* Wr1   = (const float*)d_in[5];
  const float* br1   = (const float*)d_in[6];
  const float* att1  = (const float*)d_in[7];
  const float* bias1 = (const float*)d_in[8];
  const float* Wl2   = (const float*)d_in[9];
  const float* bl2   = (const float*)d_in[10];
  const float* Wr2   = (const float*)d_in[11];
  const float* br2   = (const float*)d_in[12];
  const float* att2  = (const float*)d_in[13];
  const float* bias2 = (const float*)d_in[14];
  const float* Wc    = (const float*)d_in[15];
  const float* bc    = (const float*)d_in[16];
  float* out = (float*)d_out;

  const int N  = in_sizes[0] / F_IN;
  const int E  = in_sizes[1] / 2;
  const int E2 = E + N;
  const int nbuk = (N + 255) >> 8;   // 391 for N=100K (<=512 assumed)
  const int nscat = (E2 + 8191) / 8192;
  const int ngemm = (N + 63) / 64;

  // Workspace layout
  float* ws   = (float*)d_ws;
  unsigned short* xl1 = (unsigned short*)ws;   // N*64 bf16
  float* xr1  = (float*)(xl1 + (size_t)N * 64);// N*64 fp32
  unsigned short* xl2 = (unsigned short*)(xr1 + (size_t)N * 64); // N*16 bf16
  float* xr2  = (float*)(xl2 + (size_t)N * 16);// N*16 fp32 (byte off N*32: 4B-aligned)
  float* h2   = xr2 + (size_t)N * 16;          // N*16
  int* irow   = (int*)(h2 + (size_t)N * 16);   // N+1
  int* icsr   = irow + (N + 1);                // E2
  int* gcnt   = icsr + E2;                     // 512
  int* gbase  = gcnt + 512;                    // 512+1
  int* gbuk   = gbase + 513 + 2;               // nbuk*BUKPAD
  unsigned short* wfrag =
      (unsigned short*)(((uintptr_t)(gbuk + (size_t)nbuk * BUKPAD) + 15) & ~(uintptr_t)15);
  float* sums = (float*)(wfrag + 16384);       // NB*16
  float* cnts = sums + NB * CH2_;              // NB

  // ---- setup (independent of everything else) ----
  fill_f32<<<1, 256, 0, stream>>>((float*)gcnt, 0.0f, 512);
  build_wfrag<<<64, 256, 0, stream>>>(Wl1, Wr1, wfrag);

  // ---- MEGA: bucket_scatter || layer-1 MFMA GEMM (independent chains) ----
  mega_scatter_gemm<<<nscat + ngemm, 256, 0, stream>>>(
      ei, E, E2, gcnt, gbuk, nscat, x, wfrag, bl1, br1, xl1, xr1, N);

  // ---- CSR finish ----
  bucket_prefix<<<1, 64, 0, stream>>>(gcnt, nbuk, gbase, irow, N);
  bucket_csr<<<nbuk, 256, 0, stream>>>(gcnt, gbase, gbuk, irow, icsr, N);

  // ---- fused layer 1 + layer-2 linear transforms ----
  fused_layer1<<<(N + 3) / 4, 256, 0, stream>>>(
      irow, icsr, xl1, xr1, att1, bias1, Wl2, bl2, Wr2, br2, xl2, xr2, N);

  // ---- fused layer 2 ----
  fused_layer2<<<(N + 15) / 16, 256, 0, stream>>>(irow, icsr, xl2, xr2, att2, bias2, h2, N);

  // ---- pooling + classifier ----
  fill_f32<<<1, 256, 0, stream>>>(sums, 0.0f, NB * CH2_ + NB);
  pool_kernel<<<256, 256, 0, stream>>>(h2, batch, sums, cnts, N);
  classifier<<<1, 64, 0, stream>>>(sums, cnts, Wc, bc, out);
}